// Round 1
// baseline (55.322 us; speedup 1.0000x reference)
//
#include <hip/hip_runtime.h>
#include <math.h>

#define NROWS 8192
#define DDIM  128
#define BATCH 64

__device__ __forceinline__ void f4_add(float4& a, const float4 b) {
    a.x += b.x; a.y += b.y; a.z += b.z; a.w += b.w;
}
__device__ __forceinline__ void f4_fma_sq(float4& a, const float4 b) {
    a.x = fmaf(b.x, b.x, a.x); a.y = fmaf(b.y, b.y, a.y);
    a.z = fmaf(b.z, b.z, a.z); a.w = fmaf(b.w, b.w, a.w);
}
__device__ __forceinline__ void f4_max(float4& a, const float4 b) {
    a.x = fmaxf(a.x, b.x); a.y = fmaxf(a.y, b.y);
    a.z = fmaxf(a.z, b.z); a.w = fmaxf(a.w, b.w);
}
__device__ __forceinline__ void f4_min(float4& a, const float4 b) {
    a.x = fminf(a.x, b.x); a.y = fminf(a.y, b.y);
    a.z = fminf(a.z, b.z); a.w = fminf(a.w, b.w);
}

// Stage 1: each block reduces one (batch b, row-chunk c) to 4 stat planes of 128 floats.
// Layout in ws: float ws[B][nchunk][4][128]  (stat: 0=sum, 1=sumsq, 2=max, 3=min)
__global__ __launch_bounds__(256) void agg_stage1(const float* __restrict__ in,
                                                  float* __restrict__ ws,
                                                  int nchunk) {
    const int blk = blockIdx.x;
    const int b = blk / nchunk;
    const int c = blk % nchunk;
    const int rows = NROWS / nchunk;          // multiple of 8 for nchunk <= 1024 pow2
    const int tid = threadIdx.x;
    const int d4 = tid & 31;                  // float4 column index (d = 4*d4 .. 4*d4+3)
    const int rg = tid >> 5;                  // row group 0..7

    const float4* __restrict__ base =
        (const float4*)(in + (size_t)b * NROWS * DDIM);

    float4 sum = make_float4(0.f, 0.f, 0.f, 0.f);
    float4 sq  = make_float4(0.f, 0.f, 0.f, 0.f);
    float4 mx  = make_float4(-INFINITY, -INFINITY, -INFINITY, -INFINITY);
    float4 mn  = make_float4( INFINITY,  INFINITY,  INFINITY,  INFINITY);

    const int row0 = c * rows;
    const int row1 = row0 + rows;
    for (int r = row0 + rg; r < row1; r += 8) {
        float4 v = base[(size_t)r * (DDIM / 4) + d4];
        f4_add(sum, v);
        f4_fma_sq(sq, v);
        f4_max(mx, v);
        f4_min(mn, v);
    }

    __shared__ float4 s_sum[256];
    __shared__ float4 s_sq[256];
    __shared__ float4 s_mx[256];
    __shared__ float4 s_mn[256];
    s_sum[tid] = sum; s_sq[tid] = sq; s_mx[tid] = mx; s_mn[tid] = mn;
    __syncthreads();

    if (tid < 32) {
        for (int r = 1; r < 8; ++r) {
            const int i = r * 32 + tid;
            f4_add(sum, s_sum[i]);
            f4_add(sq,  s_sq[i]);
            f4_max(mx,  s_mx[i]);
            f4_min(mn,  s_mn[i]);
        }
        float* wsb = ws + ((size_t)(b * nchunk + c) * 4) * DDIM;
        ((float4*)(wsb + 0 * DDIM))[tid] = sum;
        ((float4*)(wsb + 1 * DDIM))[tid] = sq;
        ((float4*)(wsb + 2 * DDIM))[tid] = mx;
        ((float4*)(wsb + 3 * DDIM))[tid] = mn;
    }
}

// Stage 2: one thread per (b, d); combine nchunk partials, emit 5 outputs.
__global__ __launch_bounds__(256) void agg_stage2(const float* __restrict__ ws,
                                                  float* __restrict__ out,
                                                  int nchunk) {
    const int g = blockIdx.x * blockDim.x + threadIdx.x;
    if (g >= BATCH * DDIM) return;
    const int b = g / DDIM;
    const int d = g % DDIM;

    float sum = 0.f, sq = 0.f;
    float mx = -INFINITY, mn = INFINITY;
    for (int c = 0; c < nchunk; ++c) {
        const float* p = ws + ((size_t)(b * nchunk + c) * 4) * DDIM;
        sum += p[0 * DDIM + d];
        sq  += p[1 * DDIM + d];
        mx = fmaxf(mx, p[2 * DDIM + d]);
        mn = fminf(mn, p[3 * DDIM + d]);
    }
    const float inv_n = 1.f / (float)NROWS;
    const float mean = sum * inv_n;
    const float var = fmaxf(0.f, sq * inv_n - mean * mean);
    const float stdv = sqrtf(var);

    float* ob = out + (size_t)b * 5 * DDIM;
    ob[0 * DDIM + d] = mean;
    ob[1 * DDIM + d] = mx;
    ob[2 * DDIM + d] = mn;
    ob[3 * DDIM + d] = sum;
    ob[4 * DDIM + d] = stdv;
}

extern "C" void kernel_launch(void* const* d_in, const int* in_sizes, int n_in,
                              void* d_out, int out_size, void* d_ws, size_t ws_size,
                              hipStream_t stream) {
    const float* in = (const float*)d_in[0];
    float* out = (float*)d_out;
    float* ws = (float*)d_ws;

    // Pick nchunk (power of two) that fits the workspace: B*nchunk*4*128 floats.
    int nchunk = 32;
    while (nchunk > 1 &&
           (size_t)BATCH * nchunk * 4 * DDIM * sizeof(float) > ws_size) {
        nchunk >>= 1;
    }

    agg_stage1<<<BATCH * nchunk, 256, 0, stream>>>(in, ws, nchunk);

    const int total = BATCH * DDIM;
    agg_stage2<<<(total + 255) / 256, 256, 0, stream>>>(ws, out, nchunk);
}